// Round 1
// baseline (1161.912 us; speedup 1.0000x reference)
//
#include <hip/hip_runtime.h>

// FHETinyGPT forward: emb-gather -> q/k/v proj -> QK^T+poly-act -> PV -> wo -> logits.
// All matmuls are bf16 MFMA gemm_bt (C = A * B^T, A[M,K], B[N,K], both row-major,
// K-contiguous), m97-structure: 128x128 tile, BK=32, 4 waves, global_load_lds w=16.

typedef __bf16 bf16_t;
typedef __bf16 bf16x8 __attribute__((ext_vector_type(8)));
typedef __bf16 bf16x4 __attribute__((ext_vector_type(4)));
typedef float  f32x4  __attribute__((ext_vector_type(4)));

#define VOCAB 32000
#define DIM   1024
#define BATCH 4
#define SEQ   2048
#define BT    (BATCH*SEQ)   // 8192

__device__ __forceinline__ void gload_lds16(const void* g, void* l) {
    __builtin_amdgcn_global_load_lds(
        (const __attribute__((address_space(1))) void*)g,
        (__attribute__((address_space(3))) void*)l,
        16, 0, 0);
}

// ---------------- weight cast f32 -> bf16 (vectorized float4 -> bf16x4) -------------
__global__ void cast_f32_to_bf16(const float* __restrict__ in, bf16_t* __restrict__ out, int n4) {
    int i = blockIdx.x * blockDim.x + threadIdx.x;
    if (i < n4) {
        float4 v = ((const float4*)in)[i];
        bf16x4 o;
        o.x = (bf16_t)v.x; o.y = (bf16_t)v.y; o.z = (bf16_t)v.z; o.w = (bf16_t)v.w;
        ((bf16x4*)out)[i] = o;
    }
}

// ---------------- h = emb_w[x] * 0.01 -> bf16 [BT, DIM] ----------------------------
__global__ void embed_gather(const int* __restrict__ x, const float* __restrict__ emb,
                             bf16_t* __restrict__ h) {
    const int tok = blockIdx.x;          // 0..BT-1
    const int row = x[tok];
    const float4* src = (const float4*)(emb + (long)row * DIM);
    bf16x4* dst = (bf16x4*)(h + (long)tok * DIM);
    int j = threadIdx.x;                 // 0..255 == DIM/4
    float4 v = src[j];
    bf16x4 o;
    o.x = (bf16_t)(v.x * 0.01f); o.y = (bf16_t)(v.y * 0.01f);
    o.z = (bf16_t)(v.z * 0.01f); o.w = (bf16_t)(v.w * 0.01f);
    dst[j] = o;
}

// ---------------- gemm_bt: C[M,N] = epi(scale * A[M,K] @ B[N,K]^T) ------------------
// 128x128 tile, BK=32, 256 threads = 4 waves (2x2), each wave 64x64 out (4x4 frags of
// 16x16x32 bf16 MFMA). A/B staged via global_load_lds dwordx4 into linear LDS.
// ACT: 0 = scale only; 1 = fhe_act(scale*acc) = 0.1 s^2 + 0.1 s.
template<int ACT, typename CT>
__global__ __launch_bounds__(256) void gemm_bt(
    const bf16_t* __restrict__ A, const bf16_t* __restrict__ B, CT* __restrict__ C,
    int M, int N, int K, long sA, long sB, long sC, float scale)
{
    __shared__ __align__(16) bf16_t lsA[128 * 32];
    __shared__ __align__(16) bf16_t lsB[128 * 32];

    const int bz = blockIdx.z;
    A += (long)bz * sA;  B += (long)bz * sB;  C += (long)bz * sC;

    const int tm = blockIdx.y, tn = blockIdx.x;
    const int t = threadIdx.x;
    const int lane = t & 63, wave = t >> 6;
    const int wm = (wave >> 1) * 64;     // wave's row offset in 128-tile
    const int wn = (wave & 1) * 64;      // wave's col offset

    // staging: thread t loads 16B = 8 bf16; row = t/4 (+64 second call), col = (t%4)*8
    const int srow = t >> 2;
    const int scol = (t & 3) * 8;
    const bf16_t* gA = A + (long)(tm * 128 + srow) * K + scol;
    const bf16_t* gB = B + (long)(tn * 128 + srow) * K + scol;
    bf16_t* lA = &lsA[srow * 32 + scol];
    bf16_t* lB = &lsB[srow * 32 + scol];

    f32x4 acc[4][4];
#pragma unroll
    for (int i = 0; i < 4; ++i)
#pragma unroll
        for (int j = 0; j < 4; ++j)
            acc[i][j] = (f32x4){0.f, 0.f, 0.f, 0.f};

    const int arow = lane & 15;          // fragment row within 16
    const int acol = (lane >> 4) * 8;    // k-offset within 32

    for (int k0 = 0; k0 < K; k0 += 32) {
        __syncthreads();                 // all waves done reading previous tile
        gload_lds16(gA + k0,                lA);
        gload_lds16(gA + k0 + 64 * (long)K, lA + 64 * 32);
        gload_lds16(gB + k0,                lB);
        gload_lds16(gB + k0 + 64 * (long)K, lB + 64 * 32);
        __syncthreads();                 // compiler drains vmcnt(0) before barrier

        bf16x8 af[4], bfr[4];
#pragma unroll
        for (int i = 0; i < 4; ++i) {
            af[i]  = *(const bf16x8*)&lsA[(wm + i * 16 + arow) * 32 + acol];
            bfr[i] = *(const bf16x8*)&lsB[(wn + i * 16 + arow) * 32 + acol];
        }
#pragma unroll
        for (int i = 0; i < 4; ++i)
#pragma unroll
            for (int j = 0; j < 4; ++j)
                acc[i][j] = __builtin_amdgcn_mfma_f32_16x16x32_bf16(af[i], bfr[j], acc[i][j], 0, 0, 0);
    }

    // epilogue: C/D layout (m89/m91-verified): col = lane&15, row = (lane>>4)*4 + reg
    const int crow0 = tm * 128 + wm + (lane >> 4) * 4;
    const int ccol0 = tn * 128 + wn + (lane & 15);
#pragma unroll
    for (int i = 0; i < 4; ++i)
#pragma unroll
        for (int j = 0; j < 4; ++j)
#pragma unroll
            for (int r = 0; r < 4; ++r) {
                float s = acc[i][j][r] * scale;
                if (ACT) s = s * s * 0.1f + s * 0.1f;
                C[(long)(crow0 + i * 16 + r) * N + (ccol0 + j * 16)] = (CT)s;
            }
}

// -----------------------------------------------------------------------------------
extern "C" void kernel_launch(void* const* d_in, const int* in_sizes, int n_in,
                              void* d_out, int out_size, void* d_ws, size_t ws_size,
                              hipStream_t stream) {
    const int*   x    = (const int*)d_in[0];
    const float* emb  = (const float*)d_in[1];
    const float* wq   = (const float*)d_in[2];
    const float* wk   = (const float*)d_in[3];
    const float* wv   = (const float*)d_in[4];
    const float* wo   = (const float*)d_in[5];
    const float* wout = (const float*)d_in[6];
    float* logits = (float*)d_out;

    char* ws = (char*)d_ws;
    size_t off = 0;
    auto alloc = [&](size_t bytes) {
        char* p = ws + off;
        off += (bytes + 255) & ~(size_t)255;
        return p;
    };
    bf16_t* hb    = (bf16_t*)alloc((size_t)BT * DIM * 2);        // h   [8192,1024]
    bf16_t* qb    = (bf16_t*)alloc((size_t)BT * DIM * 2);        // q
    bf16_t* kb    = (bf16_t*)alloc((size_t)BT * DIM * 2);        // k
    bf16_t* vtb   = (bf16_t*)alloc((size_t)BATCH * DIM * SEQ * 2); // v^T [b][1024,2048]
    bf16_t* attnb = (bf16_t*)alloc((size_t)BATCH * SEQ * SEQ * 2); // act(attn) [b][2048,2048]
    bf16_t* o1b   = (bf16_t*)alloc((size_t)BT * DIM * 2);        // PV out
    bf16_t* o2b   = (bf16_t*)alloc((size_t)BT * DIM * 2);        // after wo
    bf16_t* wqb   = (bf16_t*)alloc((size_t)DIM * DIM * 2);
    bf16_t* wkb   = (bf16_t*)alloc((size_t)DIM * DIM * 2);
    bf16_t* wvb   = (bf16_t*)alloc((size_t)DIM * DIM * 2);
    bf16_t* wob   = (bf16_t*)alloc((size_t)DIM * DIM * 2);
    bf16_t* woutb = (bf16_t*)alloc((size_t)VOCAB * DIM * 2);

    // weight casts
    {
        int n4 = DIM * DIM / 4;                     // 262144 -> 1024 blocks
        cast_f32_to_bf16<<<n4 / 256, 256, 0, stream>>>(wq, wqb, n4);
        cast_f32_to_bf16<<<n4 / 256, 256, 0, stream>>>(wk, wkb, n4);
        cast_f32_to_bf16<<<n4 / 256, 256, 0, stream>>>(wv, wvb, n4);
        cast_f32_to_bf16<<<n4 / 256, 256, 0, stream>>>(wo, wob, n4);
        int n4o = VOCAB * DIM / 4;                  // 8192000 -> 32000 blocks
        cast_f32_to_bf16<<<n4o / 256, 256, 0, stream>>>(wout, woutb, n4o);
    }

    // h = emb[x] * 0.01
    embed_gather<<<BT, 256, 0, stream>>>(x, emb, hb);

    dim3 blk(256);
    // q = (h @ wq^T) * 0.01 ; k likewise                 [8192,1024]
    gemm_bt<0, bf16_t><<<dim3(DIM / 128, BT / 128, 1), blk, 0, stream>>>(
        hb, wqb, qb, BT, DIM, DIM, 0, 0, 0, 0.01f);
    gemm_bt<0, bf16_t><<<dim3(DIM / 128, BT / 128, 1), blk, 0, stream>>>(
        hb, wkb, kb, BT, DIM, DIM, 0, 0, 0, 0.01f);
    // v^T[b][d,s] = 0.1 * sum_e wv[d,e] h[b,s,e]         [1024,2048] per batch
    gemm_bt<0, bf16_t><<<dim3(SEQ / 128, DIM / 128, BATCH), blk, 0, stream>>>(
        wvb, hb, vtb, DIM, SEQ, DIM, 0, (long)SEQ * DIM, (long)DIM * SEQ, 0.1f);
    // attn = fhe_act(0.01 * q[b] @ k[b]^T)               [2048,2048] per batch
    gemm_bt<1, bf16_t><<<dim3(SEQ / 128, SEQ / 128, BATCH), blk, 0, stream>>>(
        qb, kb, attnb, SEQ, SEQ, DIM,
        (long)SEQ * DIM, (long)SEQ * DIM, (long)SEQ * SEQ, 0.01f);
    // o1 = 0.01 * attn[b] @ vT[b]^T                      [2048,1024] per batch
    gemm_bt<0, bf16_t><<<dim3(DIM / 128, SEQ / 128, BATCH), blk, 0, stream>>>(
        attnb, vtb, o1b, SEQ, DIM, SEQ,
        (long)SEQ * SEQ, (long)DIM * SEQ, (long)SEQ * DIM, 0.01f);
    // o2 = 0.1 * o1 @ wo^T                               [8192,1024]
    gemm_bt<0, bf16_t><<<dim3(DIM / 128, BT / 128, 1), blk, 0, stream>>>(
        o1b, wob, o2b, BT, DIM, DIM, 0, 0, 0, 0.1f);
    // logits = o2 @ wout^T  -> f32 d_out                 [8192,32000]
    gemm_bt<0, float><<<dim3(VOCAB / 128, BT / 128, 1), blk, 0, stream>>>(
        o2b, woutb, logits, BT, VOCAB, DIM, 0, 0, 0, 1.0f);
}